// Round 2
// baseline (372.111 us; speedup 1.0000x reference)
//
#include <hip/hip_runtime.h>

// Attention_76459007804089: M=8192 graphs x 64 nodes x 128 dims, all fp32.
//   q_g = h[g] @ a ; e_i = dot(x_i, q_g) ; att = segment_softmax(exp(e)) ;
//   out[g] = sum_i att_i * x_i
// Fully fused: one 256-thread block per graph; x read from HBM exactly once.

#define NPG  64    // nodes per graph (batch_num_nodes is uniformly 64)
#define DDIM 128   // d_h == d_x
#define SROW 132   // padded LDS row stride in floats (528 B, 16B-aligned, breaks pow2)

typedef __attribute__((ext_vector_type(4))) float f32x4;

__global__ __launch_bounds__(256) void gat_softmax_kernel(
    const float* __restrict__ h,
    const float* __restrict__ x,
    const float* __restrict__ a,
    float* __restrict__ out)
{
    const int g = blockIdx.x;
    const int t = threadIdx.x;

    __shared__ __align__(16) float xs[NPG * SROW];   // 33792 B padded x-tile
    __shared__ float hq[DDIM];
    __shared__ float qpart[2][DDIM];
    __shared__ float q[DDIM];
    __shared__ __align__(16) float epart[256];
    __shared__ float att[NPG];
    __shared__ float opart[2][DDIM];

    // ---- Phase A: stage x tile (64x128 fp32 = 32 KB) into LDS, float4 coalesced
    const f32x4* xg = reinterpret_cast<const f32x4*>(x + (size_t)g * (NPG * DDIM));
    #pragma unroll
    for (int it = 0; it < 8; ++it) {
        int c = it * 256 + t;            // chunk id; 32 float4-chunks per row
        f32x4 v = xg[c];
        int row = c >> 5;
        int col = c & 31;
        *reinterpret_cast<f32x4*>(&xs[row * SROW + col * 4]) = v;  // 528B stride, 16B-aligned
    }
    if (t < DDIM) hq[t] = h[(size_t)g * DDIM + t];
    __syncthreads();

    // ---- Phase B: q = h[g] @ a   (a is L2-resident; j coalesced across lanes)
    {
        const int j    = t & (DDIM - 1);
        const int half = t >> 7;          // k-range halves: 0..63 / 64..127
        const float* ap = a + (size_t)(half * 64) * DDIM + j;
        float acc = 0.f;
        #pragma unroll 16
        for (int k = 0; k < 64; ++k)
            acc += hq[half * 64 + k] * ap[(size_t)k * DDIM];   // hq: wave-uniform broadcast
        qpart[half][j] = acc;
    }
    __syncthreads();
    if (t < DDIM) q[t] = qpart[0][t] + qpart[1][t];
    __syncthreads();

    // ---- Phase C: e partials. thread -> (node i = t/4, quarter = t&3, 32 dims)
    {
        const int i       = t >> 2;
        const int quarter = t & 3;
        const float* xrow = &xs[i * SROW + quarter * 32];
        const float* qq   = &q[quarter * 32];
        float acc = 0.f;
        #pragma unroll
        for (int c = 0; c < 8; ++c) {
            f32x4 v = *reinterpret_cast<const f32x4*>(xrow + c * 4);   // 16B-aligned
            acc += v[0] * qq[c*4] + v[1] * qq[c*4+1] + v[2] * qq[c*4+2] + v[3] * qq[c*4+3];
        }
        epart[t] = acc;
    }
    __syncthreads();

    // ---- Softmax over the 64 nodes (wave 0 only; full 64-lane butterfly)
    if (t < NPG) {
        f32x4 p = *reinterpret_cast<const f32x4*>(&epart[4 * t]);
        float e  = p[0] + p[1] + p[2] + p[3];
        float ex = expf(e);               // unstabilized, faithful to reference
        float z  = ex;
        #pragma unroll
        for (int m = 32; m >= 1; m >>= 1)
            z += __shfl_xor(z, m, 64);
        att[t] = ex / z;
    }
    __syncthreads();

    // ---- Phase D: out[j] = sum_i att_i * xs[i][j]
    // thread -> (dim j = t&127, node half grp = t>>7); lane-consecutive j => 2-way LDS (free)
    {
        const int j   = t & (DDIM - 1);
        const int grp = t >> 7;
        float acc = 0.f;
        #pragma unroll
        for (int k = 0; k < 32; ++k) {
            int i = grp * 32 + k;
            acc += att[i] * xs[i * SROW + j];   // att[i]: wave-uniform broadcast
        }
        opart[grp][j] = acc;
    }
    __syncthreads();

    if (t < DDIM)
        out[(size_t)g * DDIM + t] = opart[0][t] + opart[1][t];
}

extern "C" void kernel_launch(void* const* d_in, const int* in_sizes, int n_in,
                              void* d_out, int out_size, void* d_ws, size_t ws_size,
                              hipStream_t stream) {
    const float* h = (const float*)d_in[0];   // (M, 128) fp32
    const float* x = (const float*)d_in[1];   // (N, 128) fp32
    const float* a = (const float*)d_in[2];   // (128, 128) fp32
    // d_in[3] = batch_num_nodes (int32): uniformly 64 -> node n maps to graph n/64
    float* out = (float*)d_out;               // (M, 128) fp32

    const int m = in_sizes[0] / DDIM;         // 8192 graphs
    gat_softmax_kernel<<<m, 256, 0, stream>>>(h, x, a, out);
}